// Round 5
// baseline (231.135 us; speedup 1.0000x reference)
//
#include <hip/hip_runtime.h>

#define BS 16
#define NN 50000
#define SEQ 9
#define IC 32
#define OC 32
#define FAN 320
#define GROUPS 64
#define MTILES_PER_B (NN / 16)          // 3125
#define TPX (2 * MTILES_PER_B)          // tiles per XCD (2 batches) = 6250
#define KBLK 2048                       // kmfma blocks (4 waves each) -> 8 blocks/CU
#define WPX (KBLK / 8 * 4)              // waves per XCD = 1024
#define WLN (SEQ * 2 * 64 * 4)          // wl uints (hi only) = 4608 -> 18432 B

typedef __attribute__((ext_vector_type(8))) short short8;
typedef __attribute__((ext_vector_type(4))) float f32x4;

__device__ __forceinline__ float4 fmax4(float4 a, float4 b) {
  return make_float4(fmaxf(a.x, b.x), fmaxf(a.y, b.y), fmaxf(a.z, b.z), fmaxf(a.w, b.w));
}

// pack2: one uint = bf16(a),bf16(b). A and B sides use the same pair-order ->
// any k-permutation cancels in the dot product.
__device__ __forceinline__ unsigned pk_bf16(float a, float b) {
  unsigned r;
  asm("v_cvt_pk_bf16_f32 %0, %1, %2" : "=v"(r) : "v"(a), "v"(b));
  return r;
}

__device__ __forceinline__ void split8(const float* v, unsigned* hi, unsigned* lo) {
#pragma unroll
  for (int i = 0; i < 4; i++) {
    float a = v[2 * i], b = v[2 * i + 1];
    unsigned h = pk_bf16(a, b);
    float fa = __builtin_bit_cast(float, h << 16);
    float fb = __builtin_bit_cast(float, h & 0xFFFF0000u);
    lo[i] = pk_bf16(a - fa, b - fb);
    hi[i] = h;
  }
}

union FragU { unsigned u[4]; short8 v; };

// ---------- Pass 1: column-max partials + (optional) fp32->bf16 convert ----------
__global__ __launch_bounds__(256) void kprep(const float* __restrict__ x,
                                             float* __restrict__ partial,
                                             unsigned* __restrict__ xh) {
  int bg = blockIdx.x;
  int b = bg >> 6, g = bg & 63;
  int t = threadIdx.x;
  int q = t & 7, r = t >> 3;
  const float4* xb = (const float4*)(x + (size_t)b * NN * IC);
  unsigned* xhb = xh ? xh + (size_t)b * NN * 16 : nullptr;
  float4 m = make_float4(-INFINITY, -INFINITY, -INFINITY, -INFINITY);
  for (int n = g * 32 + r; n < NN; n += GROUPS * 32) {
    float4 v = xb[n * 8 + q];
    m = fmax4(m, v);
    if (xhb) {
      uint2 p = make_uint2(pk_bf16(v.x, v.y), pk_bf16(v.z, v.w));
      *(uint2*)&xhb[n * 16 + q * 2] = p;
    }
  }
  __shared__ float4 sm[32][8];
  sm[r][q] = m;
  __syncthreads();
  for (int s = 16; s >= 1; s >>= 1) {
    if (r < s) sm[r][q] = fmax4(sm[r][q], sm[r + s][q]);
    __syncthreads();
  }
  if (t < 8) ((float4*)(partial + bg * IC))[t] = sm[0][t];
}

// ---------- Pass 2: finish max, fold bias + gmax @ W[:,288:320] ----------
__global__ __launch_bounds__(64) void kmax_final(const float* __restrict__ partial,
                                                 const float* __restrict__ W,
                                                 const float* __restrict__ bias,
                                                 float* __restrict__ gcontrib) {
  int b = blockIdx.x, t = threadIdx.x;
  __shared__ float gmax[IC];
  if (t < IC) {
    float m = -INFINITY;
    for (int g = 0; g < GROUPS; g++) m = fmaxf(m, partial[(b * GROUPS + g) * IC + t]);
    gmax[t] = m;
  }
  __syncthreads();
  if (t < OC) {
    float acc = bias[t];
#pragma unroll
    for (int c = 0; c < IC; c++) acc += gmax[c] * W[t * FAN + SEQ * IC + c];
    gcontrib[b * OC + t] = acc;
  }
}

// ---------- Pass 3: W[:,0:288] -> bf16 (hi only), MFMA-fragment order ----------
// element (s,n,l,e):  o = n*16 + (l&15), k = s*32 + (l>>4)*8 + e
__global__ __launch_bounds__(256) void kconvW(const float* __restrict__ W,
                                              unsigned* __restrict__ wfrag) {
  int slot = blockIdx.x * 256 + threadIdx.x;
  if (slot >= SEQ * 2 * 64) return;
  int s = slot >> 7, rem = slot & 127;
  int n = rem >> 6, l = rem & 63;
  int o = n * 16 + (l & 15);
  int k0 = s * 32 + (l >> 4) * 8;
  const float* p = W + o * FAN + k0;
#pragma unroll
  for (int i = 0; i < 4; i++)
    wfrag[slot * 4 + i] = pk_bf16(p[2 * i], p[2 * i + 1]);
}

// ---------- Main (primary): bf16 gather + MFMA, XCD-batch-coherent ----------
__global__ __launch_bounds__(256, 8) void kmfma_bf(const unsigned* __restrict__ xh,
                                                   const int* __restrict__ idx,
                                                   const float* __restrict__ gcontrib,
                                                   const unsigned* __restrict__ wfrag,
                                                   float* __restrict__ out) {
  __shared__ __align__(16) unsigned wl[WLN]; // 18432 B -> 8 blocks/CU
  int t = threadIdx.x;
  for (int i = t; i < WLN; i += 256) wl[i] = wfrag[i];
  __syncthreads();

  int bid = blockIdx.x;
  int xcd = bid & 7, slot = bid >> 3;
  int wid = t >> 6, l = t & 63;
  int ws = slot * 4 + wid;
  int lane_lo = l & 15, kg = l >> 4;

  for (int tt = ws; tt < TPX; tt += WPX) {
    int loc = tt, bloc = 0;
    if (loc >= MTILES_PER_B) { loc -= MTILES_PER_B; bloc = 1; }
    int b = 2 * xcd + bloc;
    int nb = loc * 16;
    const unsigned* xbh = xh + (size_t)b * NN * 16;

    int j[SEQ];
    const int* ip = idx + (nb + lane_lo) * SEQ;
#pragma unroll
    for (int s = 0; s < SEQ; s++) j[s] = ip[s];

    // one dwordx4 per row per lane: bf16 row is 64 B, lane chunk = 16 B
    FragU a[SEQ];
#pragma unroll
    for (int s = 0; s < SEQ; s++)
      *(uint4*)a[s].u = *(const uint4*)(xbh + (size_t)j[s] * 16 + kg * 4);

    f32x4 acc0 = {0.f, 0.f, 0.f, 0.f};
    f32x4 acc1 = {0.f, 0.f, 0.f, 0.f};
#pragma unroll
    for (int s = 0; s < SEQ; s++) {
      short8 bh0 = *(const short8*)&wl[(s * 2 + 0) * 256 + (l << 2)];
      short8 bh1 = *(const short8*)&wl[(s * 2 + 1) * 256 + (l << 2)];
      acc0 = __builtin_amdgcn_mfma_f32_16x16x32_bf16(a[s].v, bh0, acc0, 0, 0, 0);
      acc1 = __builtin_amdgcn_mfma_f32_16x16x32_bf16(a[s].v, bh1, acc1, 0, 0, 0);
    }

    float g0 = gcontrib[b * OC + lane_lo];
    float g1 = gcontrib[b * OC + 16 + lane_lo];
#pragma unroll
    for (int jj = 0; jj < 4; jj++) {
      size_t o = ((size_t)b * NN + nb + kg * 4 + jj) * OC;
      __builtin_nontemporal_store(acc0[jj] + g0, &out[o + lane_lo]);
      __builtin_nontemporal_store(acc1[jj] + g1, &out[o + 16 + lane_lo]);
    }
  }
}

// ---------- Fallback main (small ws): round-4 path, fp32 gather + split-A ----------
__global__ __launch_bounds__(256, 8) void kmfma_f32(const float* __restrict__ x,
                                                    const int* __restrict__ idx,
                                                    const float* __restrict__ gcontrib,
                                                    const unsigned* __restrict__ wfrag,
                                                    float* __restrict__ out) {
  __shared__ __align__(16) unsigned wl[WLN];
  int t = threadIdx.x;
  for (int i = t; i < WLN; i += 256) wl[i] = wfrag[i];
  __syncthreads();

  int bid = blockIdx.x;
  int xcd = bid & 7, slot = bid >> 3;
  int wid = t >> 6, l = t & 63;
  int ws = slot * 4 + wid;
  int lane_lo = l & 15, kg = l >> 4;

  for (int tt = ws; tt < TPX; tt += WPX) {
    int loc = tt, bloc = 0;
    if (loc >= MTILES_PER_B) { loc -= MTILES_PER_B; bloc = 1; }
    int b = 2 * xcd + bloc;
    int nb = loc * 16;
    const float* xb = x + (size_t)b * NN * IC;

    int j[SEQ];
    const int* ip = idx + (nb + lane_lo) * SEQ;
#pragma unroll
    for (int s = 0; s < SEQ; s++) j[s] = ip[s];

    float4 r0[SEQ], r1[SEQ];
#pragma unroll
    for (int s = 0; s < SEQ; s++) {
      const float4* row = (const float4*)(xb + (size_t)j[s] * IC + kg * 8);
      r0[s] = row[0];
      r1[s] = row[1];
    }

    f32x4 acc0 = {0.f, 0.f, 0.f, 0.f};
    f32x4 acc1 = {0.f, 0.f, 0.f, 0.f};
#pragma unroll
    for (int s = 0; s < SEQ; s++) {
      float v[8] = {r0[s].x, r0[s].y, r0[s].z, r0[s].w,
                    r1[s].x, r1[s].y, r1[s].z, r1[s].w};
      FragU ah, al;
      split8(v, ah.u, al.u);
      short8 bh0 = *(const short8*)&wl[(s * 2 + 0) * 256 + (l << 2)];
      short8 bh1 = *(const short8*)&wl[(s * 2 + 1) * 256 + (l << 2)];
      acc0 = __builtin_amdgcn_mfma_f32_16x16x32_bf16(ah.v, bh0, acc0, 0, 0, 0);
      acc0 = __builtin_amdgcn_mfma_f32_16x16x32_bf16(al.v, bh0, acc0, 0, 0, 0);
      acc1 = __builtin_amdgcn_mfma_f32_16x16x32_bf16(ah.v, bh1, acc1, 0, 0, 0);
      acc1 = __builtin_amdgcn_mfma_f32_16x16x32_bf16(al.v, bh1, acc1, 0, 0, 0);
    }

    float g0 = gcontrib[b * OC + lane_lo];
    float g1 = gcontrib[b * OC + 16 + lane_lo];
#pragma unroll
    for (int jj = 0; jj < 4; jj++) {
      size_t o = ((size_t)b * NN + nb + kg * 4 + jj) * OC;
      __builtin_nontemporal_store(acc0[jj] + g0, &out[o + lane_lo]);
      __builtin_nontemporal_store(acc1[jj] + g1, &out[o + 16 + lane_lo]);
    }
  }
}

extern "C" void kernel_launch(void* const* d_in, const int* in_sizes, int n_in,
                              void* d_out, int out_size, void* d_ws, size_t ws_size,
                              hipStream_t stream) {
  const float* x = (const float*)d_in[0];
  const int* idx = (const int*)d_in[1];
  const float* W = (const float*)d_in[2];
  const float* bias = (const float*)d_in[3];
  float* out = (float*)d_out;

  const size_t XH_UINTS = (size_t)BS * NN * 16;          // 51.2 MB as bytes
  const size_t TAIL = (BS * GROUPS * IC + BS * OC) * 4 + WLN * 4 + 1024;
  bool big = ws_size >= XH_UINTS * 4 / 2 + TAIL;         // xh bytes = UINTS*4/2? no:

  // xh = BS*NN*16 uints = 51.2 MB exactly (16 uints/row * 4 B)
  size_t xh_bytes = XH_UINTS * sizeof(unsigned);
  big = ws_size >= xh_bytes + TAIL;

  if (big) {
    unsigned* xh = (unsigned*)d_ws;
    float* partial = (float*)((char*)d_ws + xh_bytes);
    float* gcontrib = partial + BS * GROUPS * IC;
    unsigned* wfrag = (unsigned*)(gcontrib + BS * OC);
    kprep<<<BS * GROUPS, 256, 0, stream>>>(x, partial, xh);
    kmax_final<<<BS, 64, 0, stream>>>(partial, W, bias, gcontrib);
    kconvW<<<5, 256, 0, stream>>>(W, wfrag);
    kmfma_bf<<<KBLK, 256, 0, stream>>>(xh, idx, gcontrib, wfrag, out);
  } else {
    float* partial = (float*)d_ws;
    float* gcontrib = partial + BS * GROUPS * IC;
    unsigned* wfrag = (unsigned*)(gcontrib + BS * OC);
    kprep<<<BS * GROUPS, 256, 0, stream>>>(x, partial, nullptr);
    kmax_final<<<BS, 64, 0, stream>>>(partial, W, bias, gcontrib);
    kconvW<<<5, 256, 0, stream>>>(W, wfrag);
    kmfma_f32<<<KBLK, 256, 0, stream>>>(x, idx, gcontrib, wfrag, out);
  }
}

// Round 6
// 106.233 us; speedup vs baseline: 2.1757x; 2.1757x over previous
//
#include <hip/hip_runtime.h>

#define BS 16
#define NN 50000
#define SEQ 9
#define IC 32
#define OC 32
#define FAN 320
#define GROUPS 64
#define MTILES_PER_B (NN / 16)          // 3125
#define TPX (2 * MTILES_PER_B)          // tiles per XCD (2 batches) = 6250
#define KBLK 2048                       // kmfma blocks (4 waves each)
#define WPX (KBLK / 8 * 4)              // waves per XCD = 1024
#define WLN (SEQ * 2 * 64 * 4)          // wl uints (hi only) = 4608 -> 18432 B

typedef __attribute__((ext_vector_type(8))) short short8;
typedef __attribute__((ext_vector_type(4))) float f32x4;
typedef __attribute__((ext_vector_type(4))) unsigned uint32x4;

__device__ __forceinline__ float4 fmax4(float4 a, float4 b) {
  return make_float4(fmaxf(a.x, b.x), fmaxf(a.y, b.y), fmaxf(a.z, b.z), fmaxf(a.w, b.w));
}

// pack2: one uint = bf16 pair. A and B sides use the same pair-order ->
// any k-permutation cancels in the dot product.
__device__ __forceinline__ unsigned pk_bf16(float a, float b) {
  unsigned r;
  asm("v_cvt_pk_bf16_f32 %0, %1, %2" : "=v"(r) : "v"(a), "v"(b));
  return r;
}

__device__ __forceinline__ void split8(const float* v, unsigned* hi, unsigned* lo) {
#pragma unroll
  for (int i = 0; i < 4; i++) {
    float a = v[2 * i], b = v[2 * i + 1];
    unsigned h = pk_bf16(a, b);
    float fa = __builtin_bit_cast(float, h << 16);
    float fb = __builtin_bit_cast(float, h & 0xFFFF0000u);
    lo[i] = pk_bf16(a - fa, b - fb);
    hi[i] = h;
  }
}

union FragU { unsigned u[4]; short8 v; };

// ---------- Pass 1: column-max partials + fp32->bf16 convert ----------
// Block encoding: b = bg & 15, g = bg >> 4  =>  batch b's blocks run on XCD b%8
// (blockIdx round-robins XCDs), matching kmfma_bf's reader XCD.
__global__ __launch_bounds__(256) void kprep(const float* __restrict__ x,
                                             float* __restrict__ partial,
                                             unsigned* __restrict__ xh) {
  int bg = blockIdx.x;
  int b = bg & 15, g = bg >> 4;
  int t = threadIdx.x;
  int q = t & 7, r = t >> 3;
  const float4* xb = (const float4*)(x + (size_t)b * NN * IC);
  unsigned* xhb = xh ? xh + (size_t)b * NN * 16 : nullptr;
  float4 m = make_float4(-INFINITY, -INFINITY, -INFINITY, -INFINITY);
  for (int n = g * 32 + r; n < NN; n += GROUPS * 32) {
    float4 v = xb[n * 8 + q];
    m = fmax4(m, v);
    if (xhb) {
      uint2 p = make_uint2(pk_bf16(v.x, v.y), pk_bf16(v.z, v.w));
      *(uint2*)&xhb[n * 16 + q * 2] = p;
    }
  }
  __shared__ float4 sm[32][8];
  sm[r][q] = m;
  __syncthreads();
  for (int s = 16; s >= 1; s >>= 1) {
    if (r < s) sm[r][q] = fmax4(sm[r][q], sm[r + s][q]);
    __syncthreads();
  }
  if (t < 8) ((float4*)(partial + bg * IC))[t] = sm[0][t];
}

// ---------- Pass 2: finish max, fold bias + gmax @ W[:,288:320] ----------
__global__ __launch_bounds__(64) void kmax_final(const float* __restrict__ partial,
                                                 const float* __restrict__ W,
                                                 const float* __restrict__ bias,
                                                 float* __restrict__ gcontrib) {
  int b = blockIdx.x, t = threadIdx.x;
  __shared__ float gmax[IC];
  if (t < IC) {
    float m = -INFINITY;
    for (int g = 0; g < GROUPS; g++) m = fmaxf(m, partial[(g * 16 + b) * IC + t]);
    gmax[t] = m;
  }
  __syncthreads();
  if (t < OC) {
    float acc = bias[t];
#pragma unroll
    for (int c = 0; c < IC; c++) acc += gmax[c] * W[t * FAN + SEQ * IC + c];
    gcontrib[b * OC + t] = acc;
  }
}

// ---------- Pass 3: W[:,0:288] -> bf16 (hi only), MFMA-fragment order ----------
// element (s,n,l,e):  o = n*16 + (l&15), k = s*32 + (l>>4)*8 + e
__global__ __launch_bounds__(256) void kconvW(const float* __restrict__ W,
                                              unsigned* __restrict__ wfrag) {
  int slot = blockIdx.x * 256 + threadIdx.x;
  if (slot >= SEQ * 2 * 64) return;
  int s = slot >> 7, rem = slot & 127;
  int n = rem >> 6, l = rem & 63;
  int o = n * 16 + (l & 15);
  int k0 = s * 32 + (l >> 4) * 8;
  const float* p = W + o * FAN + k0;
#pragma unroll
  for (int i = 0; i < 4; i++)
    wfrag[slot * 4 + i] = pk_bf16(p[2 * i], p[2 * i + 1]);
}

// ---------- Main (primary): bf16 gather + MFMA, XCD-batch-coherent ----------
// XCD x owns batches {x, x+8} (both converted on XCD x by kprep).
__global__ __launch_bounds__(256, 4) void kmfma_bf(const unsigned* __restrict__ xh,
                                                   const int* __restrict__ idx,
                                                   const float* __restrict__ gcontrib,
                                                   const unsigned* __restrict__ wfrag,
                                                   float* __restrict__ out) {
  __shared__ __align__(16) unsigned wl[WLN]; // 18432 B
  int t = threadIdx.x;
  for (int i = t; i < WLN; i += 256) wl[i] = wfrag[i];
  __syncthreads();

  int bid = blockIdx.x;
  int xcd = bid & 7, slot = bid >> 3;
  int wid = t >> 6, l = t & 63;
  int ws = slot * 4 + wid;
  int lane_lo = l & 15, kg = l >> 4;

  for (int tt = ws; tt < TPX; tt += WPX) {
    int bloc = tt >= MTILES_PER_B;
    int loc = tt - bloc * MTILES_PER_B;
    int b = xcd + 8 * bloc;
    int nb = loc * 16;
    const unsigned* xbh = xh + (size_t)b * NN * 16;

    int j[SEQ];
    const int* ip = idx + (nb + lane_lo) * SEQ;
#pragma unroll
    for (int s = 0; s < SEQ; s++) j[s] = ip[s];

    f32x4 acc0 = {0.f, 0.f, 0.f, 0.f};
    f32x4 acc1 = {0.f, 0.f, 0.f, 0.f};
#pragma unroll
    for (int s = 0; s < SEQ; s++) {
      // one dwordx4 per row per lane (bf16 row = 64 B); pure value ops after.
      uint32x4 raw = *(const uint32x4*)(xbh + (size_t)j[s] * 16 + kg * 4);
      short8 av = __builtin_bit_cast(short8, raw);
      short8 bh0 = *(const short8*)&wl[(s * 2 + 0) * 256 + (l << 2)];
      short8 bh1 = *(const short8*)&wl[(s * 2 + 1) * 256 + (l << 2)];
      acc0 = __builtin_amdgcn_mfma_f32_16x16x32_bf16(av, bh0, acc0, 0, 0, 0);
      acc1 = __builtin_amdgcn_mfma_f32_16x16x32_bf16(av, bh1, acc1, 0, 0, 0);
    }

    // D layout: col = lane&15, row = (lane>>4)*4 + reg  [m89-verified]
    float g0 = gcontrib[b * OC + lane_lo];
    float g1 = gcontrib[b * OC + 16 + lane_lo];
#pragma unroll
    for (int jj = 0; jj < 4; jj++) {
      size_t o = ((size_t)b * NN + nb + kg * 4 + jj) * OC;
      __builtin_nontemporal_store(acc0[jj] + g0, &out[o + lane_lo]);
      __builtin_nontemporal_store(acc1[jj] + g1, &out[o + 16 + lane_lo]);
    }
  }
}

// ---------- Fallback main (small ws): fp32 gather + split-A (round-4 path) ----------
__global__ __launch_bounds__(256, 8) void kmfma_f32(const float* __restrict__ x,
                                                    const int* __restrict__ idx,
                                                    const float* __restrict__ gcontrib,
                                                    const unsigned* __restrict__ wfrag,
                                                    float* __restrict__ out) {
  __shared__ __align__(16) unsigned wl[WLN];
  int t = threadIdx.x;
  for (int i = t; i < WLN; i += 256) wl[i] = wfrag[i];
  __syncthreads();

  int bid = blockIdx.x;
  int xcd = bid & 7, slot = bid >> 3;
  int wid = t >> 6, l = t & 63;
  int ws = slot * 4 + wid;
  int lane_lo = l & 15, kg = l >> 4;

  for (int tt = ws; tt < TPX; tt += WPX) {
    int bloc = tt >= MTILES_PER_B;
    int loc = tt - bloc * MTILES_PER_B;
    int b = 2 * xcd + bloc;
    int nb = loc * 16;
    const float* xb = x + (size_t)b * NN * IC;

    int j[SEQ];
    const int* ip = idx + (nb + lane_lo) * SEQ;
#pragma unroll
    for (int s = 0; s < SEQ; s++) j[s] = ip[s];

    f32x4 acc0 = {0.f, 0.f, 0.f, 0.f};
    f32x4 acc1 = {0.f, 0.f, 0.f, 0.f};
#pragma unroll
    for (int s = 0; s < SEQ; s++) {
      const float4* row = (const float4*)(xb + (size_t)j[s] * IC + kg * 8);
      float4 q0 = row[0], q1 = row[1];
      float v[8] = {q0.x, q0.y, q0.z, q0.w, q1.x, q1.y, q1.z, q1.w};
      FragU ah, al;
      split8(v, ah.u, al.u);
      short8 bh0 = *(const short8*)&wl[(s * 2 + 0) * 256 + (l << 2)];
      short8 bh1 = *(const short8*)&wl[(s * 2 + 1) * 256 + (l << 2)];
      acc0 = __builtin_amdgcn_mfma_f32_16x16x32_bf16(ah.v, bh0, acc0, 0, 0, 0);
      acc0 = __builtin_amdgcn_mfma_f32_16x16x32_bf16(al.v, bh0, acc0, 0, 0, 0);
      acc1 = __builtin_amdgcn_mfma_f32_16x16x32_bf16(ah.v, bh1, acc1, 0, 0, 0);
      acc1 = __builtin_amdgcn_mfma_f32_16x16x32_bf16(al.v, bh1, acc1, 0, 0, 0);
    }

    float g0 = gcontrib[b * OC + lane_lo];
    float g1 = gcontrib[b * OC + 16 + lane_lo];
#pragma unroll
    for (int jj = 0; jj < 4; jj++) {
      size_t o = ((size_t)b * NN + nb + kg * 4 + jj) * OC;
      __builtin_nontemporal_store(acc0[jj] + g0, &out[o + lane_lo]);
      __builtin_nontemporal_store(acc1[jj] + g1, &out[o + 16 + lane_lo]);
    }
  }
}

extern "C" void kernel_launch(void* const* d_in, const int* in_sizes, int n_in,
                              void* d_out, int out_size, void* d_ws, size_t ws_size,
                              hipStream_t stream) {
  const float* x = (const float*)d_in[0];
  const int* idx = (const int*)d_in[1];
  const float* W = (const float*)d_in[2];
  const float* bias = (const float*)d_in[3];
  float* out = (float*)d_out;

  const size_t xh_bytes = (size_t)BS * NN * 16 * sizeof(unsigned); // 51.2 MB
  const size_t tail = (size_t)(BS * GROUPS * IC + BS * OC) * 4 + WLN * 4 + 1024;
  bool big = ws_size >= xh_bytes + tail;

  if (big) {
    unsigned* xh = (unsigned*)d_ws;
    float* partial = (float*)((char*)d_ws + xh_bytes);
    float* gcontrib = partial + BS * GROUPS * IC;
    unsigned* wfrag = (unsigned*)(gcontrib + BS * OC);
    kprep<<<BS * GROUPS, 256, 0, stream>>>(x, partial, xh);
    kmax_final<<<BS, 64, 0, stream>>>(partial, W, bias, gcontrib);
    kconvW<<<5, 256, 0, stream>>>(W, wfrag);
    kmfma_bf<<<KBLK, 256, 0, stream>>>(xh, idx, gcontrib, wfrag, out);
  } else {
    float* partial = (float*)d_ws;
    float* gcontrib = partial + BS * GROUPS * IC;
    unsigned* wfrag = (unsigned*)(gcontrib + BS * OC);
    kprep<<<BS * GROUPS, 256, 0, stream>>>(x, partial, nullptr);
    kmax_final<<<BS, 64, 0, stream>>>(partial, W, bias, gcontrib);
    kconvW<<<5, 256, 0, stream>>>(W, wfrag);
    kmfma_f32<<<KBLK, 256, 0, stream>>>(x, idx, gcontrib, wfrag, out);
  }
}